// Round 7
// baseline (82.564 us; speedup 1.0000x reference)
//
#include <hip/hip_runtime.h>

typedef float f32x4 __attribute__((ext_vector_type(4)));

// Padded LDS layout: matrix m occupies float4 slots [m*5, m*5+3]; slot m*5+4 is pad.
__device__ __forceinline__ int lds_slot(int p) {   // p = linear float4 row index
    return (p >> 2) * 5 + (p & 3);
}

__global__ __launch_bounds__(256) void se3_apply_pipe(
    const float* __restrict__ ext,   // [B,4,4]
    const float* __restrict__ se3,   // [N,6]
    const int*   __restrict__ idx,   // [B]
    float*       __restrict__ out,   // [B,4,4]
    int B, int N, int nt)            // nt = number of 256-matrix tiles
{
    __shared__ f32x4 lds[1280];      // 20 KiB
    const int t = threadIdx.x;
    const size_t total = (size_t)N * 24;
    const char* se3c = reinterpret_cast<const char*>(se3);
    const f32x4* extv = reinterpret_cast<const f32x4*>(ext);
    f32x4* outv = reinterpret_cast<f32x4*>(out);
    const size_t fmax = (size_t)B * 4;
    const int stride = gridDim.x;

    int k = blockIdx.x;
    if (k >= nt) return;

    // ---- prologue: gather chain for first owned tile ----
    {
        int b0 = k * 256 + t;
        int cb = (b0 < B) ? b0 : (B - 1);
        int j = idx[cb];
        // fallthrough into loop with j in hand
        // (gather issued below as "current")
        // store j in q-regs via immediate gather:
        size_t byte = (size_t)j * 24;
        size_t base = byte & ~(size_t)15;
        if (base + 32 > total) base = total - 32;
        f32x4 q0 = *reinterpret_cast<const f32x4*>(se3c + base);
        f32x4 q1 = *reinterpret_cast<const f32x4*>(se3c + base + 16);
        bool sh = (byte != base);

        while (true) {
            int knext = k + stride;
            bool have_next = (knext < nt);

            // ---- issue next tile's idx load as early as possible ----
            int jn = 0;
            if (have_next) {
                int bn = knext * 256 + t;
                int cbn = (bn < B) ? bn : (B - 1);
                jn = idx[cbn];
            }

            // ---- stage current ext tile (nontemporal, lane-contiguous) ----
            size_t fbase = (size_t)k * 1024;
            size_t g0 = fbase + t;
            size_t g1 = g0 + 256;
            size_t g2 = g0 + 512;
            size_t g3 = g0 + 768;
            f32x4 s0 = __builtin_nontemporal_load(&extv[g0 < fmax ? g0 : 0]);
            f32x4 s1 = __builtin_nontemporal_load(&extv[g1 < fmax ? g1 : 0]);
            f32x4 s2 = __builtin_nontemporal_load(&extv[g2 < fmax ? g2 : 0]);
            f32x4 s3 = __builtin_nontemporal_load(&extv[g3 < fmax ? g3 : 0]);

            __syncthreads();           // prev iteration's store-reads complete
            lds[lds_slot(t      )] = s0;
            lds[lds_slot(t + 256)] = s1;
            lds[lds_slot(t + 512)] = s2;
            lds[lds_slot(t + 768)] = s3;
            __syncthreads();

            // ---- each thread reads its own matrix (stride-5: conflict-free) ----
            f32x4 e0 = lds[t*5 + 0];
            f32x4 e1 = lds[t*5 + 1];
            f32x4 e2 = lds[t*5 + 2];
            f32x4 e3 = lds[t*5 + 3];

            // ---- issue NEXT tile's gather now; latency hides under compute ----
            f32x4 nq0 = q0, nq1 = q1;
            bool nsh = sh;
            if (have_next) {
                size_t nbyte = (size_t)jn * 24;
                size_t nbase = nbyte & ~(size_t)15;
                if (nbase + 32 > total) nbase = total - 32;
                nq0 = *reinterpret_cast<const f32x4*>(se3c + nbase);
                nq1 = *reinterpret_cast<const f32x4*>(se3c + nbase + 16);
                nsh = (nbyte != nbase);
            }

            // ---- unpack current gathered row ----
            float tx = sh ? q0.z : q0.x;
            float ty = sh ? q0.w : q0.y;
            float tz = sh ? q1.x : q0.z;
            float x  = sh ? q1.y : q0.w;
            float y  = sh ? q1.z : q1.x;
            float z  = sh ? q1.w : q1.y;

            // ---- se3 exp map (reference semantics: clip(dot, EPS)) ----
            float dot   = x*x + y*y + z*z;
            float t2    = fmaxf(dot, 1e-4f);
            float inv   = rsqrtf(t2);
            float theta = t2 * inv;          // sqrt(t2)
            float s = __sinf(theta);
            float c = __cosf(theta);
            float A  = s * inv;
            float Bc = (1.0f - c) * inv * inv;
            float Cc = (theta - s) * inv * inv * inv;

            float xx = x*x, yy = y*y, zz = z*z;
            float xy = x*y, xz = x*z, yz = y*z;

            float R00 = 1.0f - Bc*(yy + zz);
            float R01 = -A*z + Bc*xy;
            float R02 =  A*y + Bc*xz;
            float R10 =  A*z + Bc*xy;
            float R11 = 1.0f - Bc*(xx + zz);
            float R12 = -A*x + Bc*yz;
            float R20 = -A*y + Bc*xz;
            float R21 =  A*x + Bc*yz;
            float R22 = 1.0f - Bc*(xx + yy);

            float V00 = 1.0f - Cc*(yy + zz);
            float V01 = -Bc*z + Cc*xy;
            float V02 =  Bc*y + Cc*xz;
            float V10 =  Bc*z + Cc*xy;
            float V11 = 1.0f - Cc*(xx + zz);
            float V12 = -Bc*x + Cc*yz;
            float V20 = -Bc*y + Cc*xz;
            float V21 =  Bc*x + Cc*yz;
            float V22 = 1.0f - Cc*(xx + yy);

            float T0 = V00*tx + V01*ty + V02*tz;
            float T1 = V10*tx + V11*ty + V12*tz;
            float T2 = V20*tx + V21*ty + V22*tz;

            f32x4 o0, o1, o2;
            o0.x = R00*e0.x + R01*e1.x + R02*e2.x + T0*e3.x;
            o0.y = R00*e0.y + R01*e1.y + R02*e2.y + T0*e3.y;
            o0.z = R00*e0.z + R01*e1.z + R02*e2.z + T0*e3.z;
            o0.w = R00*e0.w + R01*e1.w + R02*e2.w + T0*e3.w;

            o1.x = R10*e0.x + R11*e1.x + R12*e2.x + T1*e3.x;
            o1.y = R10*e0.y + R11*e1.y + R12*e2.y + T1*e3.y;
            o1.z = R10*e0.z + R11*e1.z + R12*e2.z + T1*e3.z;
            o1.w = R10*e0.w + R11*e1.w + R12*e2.w + T1*e3.w;

            o2.x = R20*e0.x + R21*e1.x + R22*e2.x + T2*e3.x;
            o2.y = R20*e0.y + R21*e1.y + R22*e2.y + T2*e3.y;
            o2.z = R20*e0.z + R21*e1.z + R22*e2.z + T2*e3.z;
            o2.w = R20*e0.w + R21*e1.w + R22*e2.w + T2*e3.w;

            // Thread t only overwrites its OWN matrix's slots (rows 0-2); row 3
            // stays as staged ext row 3 (== correct output row 3).
            lds[t*5 + 0] = o0;
            lds[t*5 + 1] = o1;
            lds[t*5 + 2] = o2;
            __syncthreads();

            // ---- cooperative lane-contiguous nontemporal store ----
            if (g0 < fmax) __builtin_nontemporal_store(lds[lds_slot(t      )], &outv[g0]);
            if (g1 < fmax) __builtin_nontemporal_store(lds[lds_slot(t + 256)], &outv[g1]);
            if (g2 < fmax) __builtin_nontemporal_store(lds[lds_slot(t + 512)], &outv[g2]);
            if (g3 < fmax) __builtin_nontemporal_store(lds[lds_slot(t + 768)], &outv[g3]);

            if (!have_next) break;
            k = knext;
            q0 = nq0; q1 = nq1; sh = nsh;
        }
    }
}

extern "C" void kernel_launch(void* const* d_in, const int* in_sizes, int n_in,
                              void* d_out, int out_size, void* d_ws, size_t ws_size,
                              hipStream_t stream) {
    const float* ext = (const float*)d_in[0];   // [B,4,4]
    const float* se3 = (const float*)d_in[1];   // [N,6]
    const int*   idx = (const int*)d_in[2];     // [B]
    float* out = (float*)d_out;

    int B = in_sizes[2];
    int N = in_sizes[1] / 6;
    int nt = (B + 255) / 256;                   // tiles of 256 matrices
    int grid = nt < 2048 ? nt : 2048;           // 8 blocks/CU persistent
    se3_apply_pipe<<<grid, 256, 0, stream>>>(ext, se3, idx, out, B, N, nt);
}

// Round 8
// 79.301 us; speedup vs baseline: 1.0411x; 1.0411x over previous
//
#include <hip/hip_runtime.h>

typedef float f32x4 __attribute__((ext_vector_type(4)));

// Quad-permute via DPP (VALU-rate cross-lane within each group of 4 lanes).
template<int CTRL>
__device__ __forceinline__ float qperm(float v) {
    int i = __builtin_bit_cast(int, v);
    i = __builtin_amdgcn_update_dpp(0, i, CTRL, 0xF, 0xF, true);
    return __builtin_bit_cast(float, i);
}

template<int CTRL>
__device__ __forceinline__ f32x4 qperm4(f32x4 v) {
    f32x4 r;
    r.x = qperm<CTRL>(v.x);
    r.y = qperm<CTRL>(v.y);
    r.z = qperm<CTRL>(v.z);
    r.w = qperm<CTRL>(v.w);
    return r;
}

__global__ __launch_bounds__(256) void se3_apply_quad(
    const float* __restrict__ ext,   // [B,4,4]
    const float* __restrict__ se3,   // [N,6]
    const int*   __restrict__ idx,   // [B]
    float*       __restrict__ out,   // [B,4,4]
    int B, int N)
{
    const long tid = (long)blockIdx.x * 256 + threadIdx.x;  // global float4-row id
    const long m   = tid >> 2;        // matrix index
    const int  r   = (int)(tid & 3);  // row within matrix
    if (m >= B) return;

    // All 4 lanes of the quad load the same idx (same-address requests merge).
    int j = idx[m];

    // ext row r, lane-contiguous across the wave (16B/lane, each line touched once).
    const f32x4* extv = reinterpret_cast<const f32x4*>(ext);
    f32x4 E = __builtin_nontemporal_load(&extv[tid]);

    // gather se3 row as two aligned 16B loads from its 32B window (quad-shared line).
    size_t byte  = (size_t)j * 24;
    size_t base  = byte & ~(size_t)15;
    size_t total = (size_t)N * 24;
    if (base + 32 > total) base = total - 32;   // clamp keeps phase in {0,8}
    const char* se3c = reinterpret_cast<const char*>(se3);
    f32x4 q0 = *reinterpret_cast<const f32x4*>(se3c + base);
    f32x4 q1 = *reinterpret_cast<const f32x4*>(se3c + base + 16);
    bool sh = (byte != base);

    float tx = sh ? q0.z : q0.x;
    float ty = sh ? q0.w : q0.y;
    float tz = sh ? q1.x : q0.z;
    float x  = sh ? q1.y : q0.w;
    float y  = sh ? q1.z : q1.x;
    float z  = sh ? q1.w : q1.y;

    // se3 exp map coefficients (reference semantics: clip(dot, EPS))
    float dot   = x*x + y*y + z*z;
    float t2    = fmaxf(dot, 1e-4f);
    float inv   = rsqrtf(t2);
    float theta = t2 * inv;          // sqrt(t2)
    float s = __sinf(theta);
    float c = __cosf(theta);
    float A  = s * inv;
    float Bc = (1.0f - c) * inv * inv;
    float Cc = (theta - s) * inv * inv * inv;

    float xx = x*x, yy = y*y, zz = z*z;
    float xy = x*y, xz = x*z, yz = y*z;

    // This lane only needs ROW r of K and K^2 (rows of the refinement matrix).
    bool r0 = (r == 0), r1 = (r == 1), r2 = (r == 2), r3 = (r == 3);
    float kr0 = r1 ?  z : r2 ? -y : 0.0f;
    float kr1 = r0 ? -z : r2 ?  x : 0.0f;
    float kr2 = r0 ?  y : r1 ? -x : 0.0f;
    float k20 = r0 ? -(yy + zz) : r1 ? xy : r2 ? xz : 0.0f;
    float k21 = r0 ? xy : r1 ? -(xx + zz) : r2 ? yz : 0.0f;
    float k22 = r0 ? xz : r1 ? yz : r2 ? -(xx + yy) : 0.0f;
    float d0 = r0 ? 1.0f : 0.0f;
    float d1 = r1 ? 1.0f : 0.0f;
    float d2 = r2 ? 1.0f : 0.0f;

    // Row r of R = I + A*K + Bc*K^2  (all-zero for r==3)
    float R0 = d0 + A*kr0 + Bc*k20;
    float R1 = d1 + A*kr1 + Bc*k21;
    float R2 = d2 + A*kr2 + Bc*k22;
    // Row r of V = I + Bc*K + Cc*K^2, then T_r = V_r . t
    float V0 = d0 + Bc*kr0 + Cc*k20;
    float V1 = d1 + Bc*kr1 + Cc*k21;
    float V2 = d2 + Bc*kr2 + Cc*k22;
    float T  = V0*tx + V1*ty + V2*tz;

    // M row r in column order (m0..m3); bottom row = [0,0,0,1].
    float m0 = R0, m1 = R1, m2 = R2;
    float m3 = r3 ? 1.0f : T;

    // Coefficients in quad-rotation order: ck = M[r][(r+k)&3]
    float c0 = r0 ? m0 : r1 ? m1 : r2 ? m2 : m3;
    float c1 = r0 ? m1 : r1 ? m2 : r2 ? m3 : m0;
    float c2 = r0 ? m2 : r1 ? m3 : r2 ? m0 : m1;
    float c3 = r0 ? m3 : r1 ? m0 : r2 ? m1 : m2;

    // Other quad rows of E via DPP quad_perm rotations.
    f32x4 E1 = qperm4<0x39>(E);   // lane r gets E row (r+1)&3
    f32x4 E2 = qperm4<0x4E>(E);   // (r+2)&3
    f32x4 E3 = qperm4<0x93>(E);   // (r+3)&3

    f32x4 o = c0*E + c1*E1 + c2*E2 + c3*E3;

    f32x4* outv = reinterpret_cast<f32x4*>(out);
    __builtin_nontemporal_store(o, &outv[tid]);
}

extern "C" void kernel_launch(void* const* d_in, const int* in_sizes, int n_in,
                              void* d_out, int out_size, void* d_ws, size_t ws_size,
                              hipStream_t stream) {
    const float* ext = (const float*)d_in[0];   // [B,4,4]
    const float* se3 = (const float*)d_in[1];   // [N,6]
    const int*   idx = (const int*)d_in[2];     // [B]
    float* out = (float*)d_out;

    int B = in_sizes[2];
    int N = in_sizes[1] / 6;
    long threads = (long)B * 4;                 // one float4-row per thread
    int grid = (int)((threads + 255) / 256);
    se3_apply_quad<<<grid, 256, 0, stream>>>(ext, se3, idx, out, B, N);
}